// Round 6
// baseline (285.793 us; speedup 1.0000x reference)
//
#include <hip/hip_runtime.h>

typedef __attribute__((ext_vector_type(8))) _Float16 half8;
typedef __attribute__((ext_vector_type(4))) _Float16 half4;
typedef __attribute__((ext_vector_type(4))) float f32x4;

#define MFMA_K32(a, b, c) __builtin_amdgcn_mfma_f32_16x16x32_f16((a), (b), (c), 0, 0, 0)
#define MFMA_K16(a, b, c) __builtin_amdgcn_mfma_f32_16x16x16f16((a), (b), (c), 0, 0, 0)

// async global->LDS, 16B per lane; LDS dest = wave-uniform base + lane*16
__device__ inline void async16(const _Float16* g, _Float16* l) {
    __builtin_amdgcn_global_load_lds(
        (const __attribute__((address_space(1))) void*)g,
        (__attribute__((address_space(3))) void*)l, 16, 0, 0);
}

// ---------------------------------------------------------------------------
// B=32, S=512, Dm=768, H=12, d=64, M=16384.
// probs = (s*0.125+5)^2; probs /= (rowsum+1e-10); probs *= mask; ctx = probs@V
// Folded: ctx = (sum_k w_k * (mask_k v_k)) / (sum_k w_k + 1e-10)
// Q pre-scaled by 0.125 in GEMM epilogue; mask pre-multiplied into V.
// ---------------------------------------------------------------------------

// Kernel 0: X f32 -> f16
__global__ __launch_bounds__(256) void xcast(const float* __restrict__ X,
                                             _Float16* __restrict__ Xh)
{
    size_t idx = ((size_t)blockIdx.x * 256 + threadIdx.x) * 8;
    float4 a = *(const float4*)(X + idx);
    float4 c = *(const float4*)(X + idx + 4);
    half8 hv;
    hv[0] = (_Float16)a.x; hv[1] = (_Float16)a.y;
    hv[2] = (_Float16)a.z; hv[3] = (_Float16)a.w;
    hv[4] = (_Float16)c.x; hv[5] = (_Float16)c.y;
    hv[6] = (_Float16)c.z; hv[7] = (_Float16)c.w;
    *(half8*)(Xh + idx) = hv;
}

// Kernel 1: weights transpose+cast: Wt[n][k] = (f16) W[k][n]
__global__ __launch_bounds__(256) void wcast_kernel(
    const float* __restrict__ W0, const float* __restrict__ W1,
    const float* __restrict__ W2,
    _Float16* __restrict__ T0, _Float16* __restrict__ T1,
    _Float16* __restrict__ T2)
{
    int z = blockIdx.z;
    const float* W = (z == 0) ? W0 : (z == 1) ? W1 : W2;
    _Float16* T = (z == 0) ? T0 : (z == 1) ? T1 : T2;
    __shared__ float tile[32][33];
    int n0 = blockIdx.x * 32, k0 = blockIdx.y * 32;
    int tx = threadIdx.x & 31, ty = threadIdx.x >> 5;
#pragma unroll
    for (int r = 0; r < 4; ++r)
        tile[ty + 8 * r][tx] = W[(size_t)(k0 + ty + 8 * r) * 768 + n0 + tx];
    __syncthreads();
#pragma unroll
    for (int r = 0; r < 4; ++r)
        T[(size_t)(n0 + ty + 8 * r) * 768 + k0 + tx] =
            (_Float16)tile[tx][ty + 8 * r];
}

// ---------------------------------------------------------------------------
// Kernel 2: fused QKV GEMM — EXACT R4 code (passed, 95 µs, 0 bank conflicts).
// BK=64; XOR swizzle on 16B chunks (LDS chunk j of row holds global chunk
// j ^ (row&7)). Q out pre-scaled 0.125. V out transposed [B,H,64,S], premasked.
// ---------------------------------------------------------------------------
__global__ __launch_bounds__(256) void qkv_gemm(
    const _Float16* __restrict__ Xh,
    const _Float16* __restrict__ W0, const _Float16* __restrict__ W1,
    const _Float16* __restrict__ W2,
    const float* __restrict__ b0, const float* __restrict__ b1,
    const float* __restrict__ b2,
    const float* __restrict__ mask,
    _Float16* __restrict__ Qo, _Float16* __restrict__ Ko,
    _Float16* __restrict__ Vo)
{
    int z = blockIdx.y / 6;
    int n0 = (blockIdx.y % 6) * 128;
    int m0 = blockIdx.x * 128;
    const _Float16* Wt = (z == 0) ? W0 : (z == 1) ? W1 : W2;
    const float* bias = (z == 0) ? b0 : (z == 1) ? b1 : b2;

    __shared__ __attribute__((aligned(16))) _Float16 As[128 * 64];  // 16 KB
    __shared__ __attribute__((aligned(16))) _Float16 Bs[128 * 64];  // 16 KB

    int t = threadIdx.x;
    int wave = t >> 6, lane = t & 63, quad = lane >> 4, l16 = lane & 15;
    int wm = (wave & 1) * 64, wn = (wave >> 1) * 64;

    int srow = t >> 3;               // 0..31 (row advances +32 per slot)
    int sg = (t & 7) ^ (srow & 7);   // global chunk this thread fetches

    const _Float16* gA = Xh + (size_t)(m0 + srow) * 768 + sg * 8;
    const _Float16* gB = Wt + (size_t)(n0 + srow) * 768 + sg * 8;
    _Float16* lA = As + t * 8;
    _Float16* lB = Bs + t * 8;

    f32x4 acc[4][4] = {};

    for (int k0 = 0; k0 < 768; k0 += 64) {
#pragma unroll
        for (int q = 0; q < 4; ++q) {
            async16(gA + (size_t)q * 32 * 768 + k0, lA + q * 2048);
            async16(gB + (size_t)q * 32 * 768 + k0, lB + q * 2048);
        }
        __syncthreads();  // drains vmcnt -> tiles staged
#pragma unroll
        for (int ks = 0; ks < 2; ++ks) {
            half8 af[4], bf[4];
#pragma unroll
            for (int i = 0; i < 4; ++i) {
                int row = wm + i * 16 + l16;
                af[i] = *(const half8*)&As[row * 64 +
                                           (((ks << 2) + quad) ^ (row & 7)) * 8];
            }
#pragma unroll
            for (int j = 0; j < 4; ++j) {
                int row = wn + j * 16 + l16;
                bf[j] = *(const half8*)&Bs[row * 64 +
                                           (((ks << 2) + quad) ^ (row & 7)) * 8];
            }
#pragma unroll
            for (int i = 0; i < 4; ++i)
#pragma unroll
                for (int j = 0; j < 4; ++j)
                    acc[i][j] = MFMA_K32(af[i], bf[j], acc[i][j]);
        }
        __syncthreads();
    }

    // epilogue: C row = wm+i*16+quad*4+r ; col = wn+j*16+l16
    float mk[4][4];
    if (z == 2) {
#pragma unroll
        for (int i = 0; i < 4; ++i) {
            int mbase = m0 + wm + i * 16 + quad * 4;
            int bb = mbase >> 9, s = mbase & 511;
#pragma unroll
            for (int r = 0; r < 4; ++r)
                mk[i][r] = mask[(size_t)bb * 512 + s + r];
        }
    }
#pragma unroll
    for (int j = 0; j < 4; ++j) {
        int n = n0 + wn + j * 16 + l16;
        float bv = bias[n];
        int hh = n >> 6, d = n & 63;
#pragma unroll
        for (int i = 0; i < 4; ++i) {
            int mbase = m0 + wm + i * 16 + quad * 4;
            int bb = mbase >> 9, s = mbase & 511;
            if (z == 0) {
                // Q, pre-scaled by 0.125 (score scale folded in)
#pragma unroll
                for (int r = 0; r < 4; ++r) {
                    size_t off = (((size_t)(bb * 12 + hh)) * 512 + s + r) * 64 + d;
                    Qo[off] = (_Float16)((acc[i][j][r] + bv) * 0.125f);
                }
            } else if (z == 1) {
#pragma unroll
                for (int r = 0; r < 4; ++r) {
                    size_t off = (((size_t)(bb * 12 + hh)) * 512 + s + r) * 64 + d;
                    Ko[off] = (_Float16)(acc[i][j][r] + bv);
                }
            } else {
                // V^T [B,H,64,S], premasked; regs = consecutive tokens -> 8B store
                half4 pk;
#pragma unroll
                for (int r = 0; r < 4; ++r)
                    pk[r] = (_Float16)((acc[i][j][r] + bv) * mk[i][r]);
                size_t off = (((size_t)(bb * 12 + hh)) * 64 + d) * 512 + s;
                *(half4*)&Vo[off] = pk;
            }
        }
    }
}

// ---------------------------------------------------------------------------
// Kernel 3: power-law attention — register-streaming, no LDS, no barriers.
// One wave per (64-query tile, head): grid (8, 12, 32), 64-thread blocks.
// Fragment addressing is EXACTLY R4's verified LDS-read layouts, with the
// global K / V^T base in place of the LDS tile:
//   K A-frag:  K[key = kb*16+l16][d = {0,32} + quad*8 ..+7]   (half8 x2)
//   V B-frag:  V^T[d = n*16+l16][keys kb*16+quad*4 ..+3]      (half4)
// Each wave re-walks a 16 KB K/V tile per kt -> L1/L2/LLC absorb re-reads
// (total K+V = 50 MB << 256 MB LLC). No __syncthreads anywhere: compiler
// free to hoist next-tile loads across MFMAs (no barrier vmcnt clamp).
// ---------------------------------------------------------------------------
__global__ __launch_bounds__(64) void attn_kernel(
    const _Float16* __restrict__ Q, const _Float16* __restrict__ K,
    const _Float16* __restrict__ Vt, float* __restrict__ out)
{
    int lane = threadIdx.x;
    int quad = lane >> 4, l16 = lane & 15;
    int h = blockIdx.y, b = blockIdx.z;
    size_t bh = (size_t)b * 12 + h;
    const _Float16* Qp = Q + bh * (512 * 64);
    const _Float16* Kp = K + bh * (512 * 64);
    const _Float16* Vp = Vt + bh * (64 * 512);
    int qbase = blockIdx.x * 64;

    // Q fragments (B-operand of 16x16x32: lane holds Q[q=l16][d=ks*32+quad*8..+7])
    half8 qf[4][2];
#pragma unroll
    for (int i = 0; i < 4; ++i)
#pragma unroll
        for (int ks = 0; ks < 2; ++ks)
            qf[i][ks] = *(const half8*)(Qp + (size_t)(qbase + i * 16 + l16) * 64 +
                                        ks * 32 + quad * 8);

    f32x4 ctx[4][4] = {};
    f32x4 rsum[4] = {};
    const half4 ones = {(_Float16)1.f, (_Float16)1.f, (_Float16)1.f, (_Float16)1.f};

    for (int kt = 0; kt < 8; ++kt) {
        int k0 = kt * 64;
#pragma unroll
        for (int kb = 0; kb < 4; ++kb) {
            // K A-fragment straight from global (16 rows x 64B segments)
            const _Float16* kr = Kp + (size_t)(k0 + kb * 16 + l16) * 64 + quad * 8;
            half8 kf0 = *(const half8*)kr;
            half8 kf1 = *(const half8*)(kr + 32);
            half4 pA[4];
#pragma unroll
            for (int i = 0; i < 4; ++i) {
                f32x4 sc = {0.f, 0.f, 0.f, 0.f};
                sc = MFMA_K32(kf0, qf[i][0], sc);
                sc = MFMA_K32(kf1, qf[i][1], sc);
                half4 p;
#pragma unroll
                for (int r = 0; r < 4; ++r) {
                    float s = sc[r] + 5.0f;   // Q pre-scaled by 0.125
                    p[r] = (_Float16)(s * s);
                }
                pA[i] = p;
                rsum[i] = MFMA_K16(p, ones, rsum[i]);
            }
            int kk = k0 + kb * 16 + quad * 4;   // keys this lane feeds to PV
#pragma unroll
            for (int n = 0; n < 4; ++n) {
                half4 vf = *(const half4*)(Vp + (size_t)(n * 16 + l16) * 512 + kk);
#pragma unroll
                for (int i = 0; i < 4; ++i)
                    ctx[i][n] = MFMA_K16(pA[i], vf, ctx[i][n]);
            }
        }
    }

    // epilogue: rsum reg r and ctx reg r both live on C row = quad*4+r
#pragma unroll
    for (int i = 0; i < 4; ++i) {
        f32x4 inv;
#pragma unroll
        for (int r = 0; r < 4; ++r)
            inv[r] = 1.0f / (rsum[i][r] + 1e-10f);
#pragma unroll
        for (int n = 0; n < 4; ++n)
#pragma unroll
            for (int r = 0; r < 4; ++r) {
                int q = qbase + i * 16 + quad * 4 + r;
                int d = n * 16 + l16;
                out[((size_t)b * 512 + q) * 768 + h * 64 + d] =
                    ctx[i][n][r] * inv[r];
            }
    }
}

// ---------------------------------------------------------------------------
extern "C" void kernel_launch(void* const* d_in, const int* in_sizes, int n_in,
                              void* d_out, int out_size, void* d_ws, size_t ws_size,
                              hipStream_t stream)
{
    const float* hs   = (const float*)d_in[0];
    const float* mask = (const float*)d_in[1];
    const float* Wq   = (const float*)d_in[2];
    const float* bq   = (const float*)d_in[3];
    const float* Wk   = (const float*)d_in[4];
    const float* bk   = (const float*)d_in[5];
    const float* Wv   = (const float*)d_in[6];
    const float* bv   = (const float*)d_in[7];
    float* out = (float*)d_out;

    char* ws = (char*)d_ws;
    _Float16* Wtq = (_Float16*)ws;            // 3 x 768*768 halves
    _Float16* Wtk = Wtq + 768 * 768;
    _Float16* Wtv = Wtk + 768 * 768;
    _Float16* Qb  = Wtv + 768 * 768;          // 3 x 16384*768 halves
    _Float16* Kb  = Qb + 16384 * 768;
    _Float16* Vb  = Kb + 16384 * 768;
    // ws use ~79 MB. Xh scratch lives in d_out (Xh 25 MB, dead before attn).
    _Float16* Xh = (_Float16*)d_out;

    xcast<<<dim3(6144), 256, 0, stream>>>(hs, Xh);
    wcast_kernel<<<dim3(24, 24, 3), 256, 0, stream>>>(Wq, Wk, Wv, Wtq, Wtk, Wtv);
    qkv_gemm<<<dim3(128, 18), 256, 0, stream>>>(Xh, Wtq, Wtk, Wtv,
                                                bq, bk, bv, mask, Qb, Kb, Vb);
    attn_kernel<<<dim3(8, 12, 32), 64, 0, stream>>>(Qb, Kb, Vb, out);
}